// Round 1
// baseline (613.817 us; speedup 1.0000x reference)
//
#include <hip/hip_runtime.h>
#include <hip/hip_bf16.h>

#define BB 8
#define NN 4096
#define DD 1024
#define HH 64

typedef __bf16 bf8v __attribute__((ext_vector_type(8)));
typedef __bf16 bf4v __attribute__((ext_vector_type(4)));
typedef float  f4v  __attribute__((ext_vector_type(4)));
typedef __hip_bfloat16 bf16;

__device__ __forceinline__ f4v mfma16x16x32(bf8v a, bf8v b, f4v c) {
    return __builtin_amdgcn_mfma_f32_16x16x32_bf16(a, b, c, 0, 0, 0);
}

// pack two f4v (8 consecutive fp32) into a bf16x8 MFMA fragment
__device__ __forceinline__ bf8v pack8(f4v a, f4v b) {
    bf8v r;
    #pragma unroll
    for (int i = 0; i < 4; ++i) { r[i] = (__bf16)a[i]; r[i + 4] = (__bf16)b[i]; }
    return r;
}

__device__ __forceinline__ bf8v ldg8(const bf16* p) { return *(const bf8v*)p; }

// Kernel 0: convert the 4 weight matrices to bf16 in workspace: [Wq | Wk | Wv | Wp]
__global__ __launch_bounds__(256) void convert_weights_kernel(
    const float* __restrict__ Wq, const float* __restrict__ Wk,
    const float* __restrict__ Wv, const float* __restrict__ Wp,
    bf16* __restrict__ cw)
{
    const int idx = blockIdx.x * 256 + threadIdx.x;
    const int t = idx >> 14;
    const int e = (idx & 16383) * 4;
    const float* src = (t == 0) ? Wq : (t == 1) ? Wk : (t == 2) ? Wv : Wp;
    f4v x = *(const f4v*)(src + e);
    bf4v r;
    #pragma unroll
    for (int i = 0; i < 4; ++i) r[i] = (__bf16)x[i];
    *(bf4v*)(cw + t * 65536 + e) = r;
}

// Kernel 1: fused q/k/v projection.
//   Even blocks: k,v projections -> exp -> se/sev atomics.
//   Odd  blocks: q projection -> sigmoid -> fp32 gate store.
// Block = 4 waves: (rhalf = which 16-row subtile of a 32-row chunk) x
//                  (hhalf = which 32 of the 64 h columns).
// Grid = 2 * 8 b * 128 chunks = 2048 blocks, 8192 waves.
// Inner loop: fully unrolled K=1024, 1-step software pipeline of A (32B/lane)
// and W (16B/lane x2) so loads stay in flight across the MFMA cluster.
__global__ __launch_bounds__(256, 4) void proj_kernel(
    const float* __restrict__ query, const float* __restrict__ key,
    const float* __restrict__ value, const bf16* __restrict__ cw,
    const float* __restrict__ bq, const float* __restrict__ bk,
    const float* __restrict__ bv,
    float* __restrict__ se, float* __restrict__ sev,
    float* __restrict__ gate)
{
    const int lane  = threadIdx.x & 63;
    const int wave  = threadIdx.x >> 6;
    const int cl    = lane & 15;   // A row (m) / C col (h) / B col
    const int quad  = lane >> 4;
    const int rhalf = wave >> 1;
    const int hhalf = wave & 1;
    const int is_q  = blockIdx.x & 1;
    const int bid   = blockIdx.x >> 1;
    const int b     = bid >> 7;
    const int chunk = bid & 127;
    const int row0  = chunk * 32 + rhalf * 16;

    const size_t abase = ((size_t)b * NN + row0 + cl) * DD + quad * 8;
    const size_t wbase = (size_t)(hhalf * 32 + cl) * DD + quad * 8;

    if (is_q) {
        // ---- q projection -> sigmoid gate ----
        const float* qp = query + abase;
        const bf16*  wq = cw + wbase;                    // cw[0] = Wq

        f4v qacc[2];
        qacc[0] = qacc[1] = (f4v){0.f, 0.f, 0.f, 0.f};

        f4v a0 = *(const f4v*)qp, a1 = *(const f4v*)(qp + 4);
        bf8v w0 = ldg8(wq), w1 = ldg8(wq + 16 * DD);

        #pragma unroll
        for (int s = 0; s < 32; ++s) {
            f4v na0, na1; bf8v nw0, nw1;
            if (s < 31) {
                const int k0 = (s + 1) * 32;
                na0 = *(const f4v*)(qp + k0); na1 = *(const f4v*)(qp + k0 + 4);
                nw0 = ldg8(wq + k0);          nw1 = ldg8(wq + 16 * DD + k0);
            }
            bf8v aq = pack8(a0, a1);
            qacc[0] = mfma16x16x32(aq, w0, qacc[0]);
            qacc[1] = mfma16x16x32(aq, w1, qacc[1]);
            if (s < 31) { a0 = na0; a1 = na1; w0 = nw0; w1 = nw1; }
        }

        // C layout: col = cl (h), row = quad*4 + r
        const size_t gbase = ((size_t)b * NN + row0 + quad * 4) * HH;
        #pragma unroll
        for (int t2 = 0; t2 < 2; ++t2) {
            const int h = hhalf * 32 + t2 * 16 + cl;
            const float bqh = bq[h];
            #pragma unroll
            for (int r = 0; r < 4; ++r) {
                float qv = qacc[t2][r] + bqh;
                float sg = 1.0f / (1.0f + __expf(-qv));
                gate[gbase + (size_t)r * HH + h] = sg;
            }
        }
    } else {
        // ---- k,v projections -> exp reduce -> atomics ----
        const float* kp = key   + abase;
        const float* vp = value + abase;
        const bf16*  wk = cw + 1 * 65536 + wbase;        // Wk
        const bf16*  wv = cw + 2 * 65536 + wbase;        // Wv

        f4v kacc[2], vacc[2];
        kacc[0] = kacc[1] = vacc[0] = vacc[1] = (f4v){0.f, 0.f, 0.f, 0.f};

        f4v ka0 = *(const f4v*)kp, ka1 = *(const f4v*)(kp + 4);
        f4v va0 = *(const f4v*)vp, va1 = *(const f4v*)(vp + 4);
        bf8v wk0 = ldg8(wk), wk1 = ldg8(wk + 16 * DD);
        bf8v wv0 = ldg8(wv), wv1 = ldg8(wv + 16 * DD);

        #pragma unroll
        for (int s = 0; s < 32; ++s) {
            f4v nka0, nka1, nva0, nva1;
            bf8v nwk0, nwk1, nwv0, nwv1;
            if (s < 31) {
                const int k0 = (s + 1) * 32;
                nka0 = *(const f4v*)(kp + k0); nka1 = *(const f4v*)(kp + k0 + 4);
                nva0 = *(const f4v*)(vp + k0); nva1 = *(const f4v*)(vp + k0 + 4);
                nwk0 = ldg8(wk + k0);          nwk1 = ldg8(wk + 16 * DD + k0);
                nwv0 = ldg8(wv + k0);          nwv1 = ldg8(wv + 16 * DD + k0);
            }
            bf8v ak = pack8(ka0, ka1);
            bf8v av = pack8(va0, va1);
            kacc[0] = mfma16x16x32(ak, wk0, kacc[0]);
            kacc[1] = mfma16x16x32(ak, wk1, kacc[1]);
            vacc[0] = mfma16x16x32(av, wv0, vacc[0]);
            vacc[1] = mfma16x16x32(av, wv1, vacc[1]);
            if (s < 31) {
                ka0 = nka0; ka1 = nka1; va0 = nva0; va1 = nva1;
                wk0 = nwk0; wk1 = nwk1; wv0 = nwv0; wv1 = nwv1;
            }
        }

        #pragma unroll
        for (int t2 = 0; t2 < 2; ++t2) {
            const int h = hhalf * 32 + t2 * 16 + cl;
            const float bkh = bk[h];
            const float bvh = bv[h];
            float sep = 0.f, sevp = 0.f;
            #pragma unroll
            for (int r = 0; r < 4; ++r) {
                float e = __expf(kacc[t2][r] + bkh);
                sep  += e;
                sevp += e * (vacc[t2][r] + bvh);
            }
            sep  += __shfl_xor(sep, 16, 64);
            sevp += __shfl_xor(sevp, 16, 64);
            sep  += __shfl_xor(sep, 32, 64);
            sevp += __shfl_xor(sevp, 32, 64);
            if (quad == 0) {
                atomicAdd(&se[b * HH + h], sep);
                atomicAdd(&sev[b * HH + h], sevp);
            }
        }
    }
}

// Kernel 2: out[b,n,:] = (gate[b,n,:] * (sev/se)[b,:]) @ Wp^T + bp
// Tile = 16 rows; 4 waves each own a 256-wide d-slice -> grid 2048 x 8192 waves.
// Reads 8 MB gate (L3-resident) + 128 KB Wp; pure write-bound on 134 MB out.
__global__ __launch_bounds__(256) void out_kernel(
    const float* __restrict__ gate, const bf16* __restrict__ cWp,
    const float* __restrict__ bp, const float* __restrict__ se,
    const float* __restrict__ sev, float* __restrict__ out)
{
    const int lane = threadIdx.x & 63;
    const int wave = threadIdx.x >> 6;
    const int cl   = lane & 15;
    const int quad = lane >> 4;
    const int b     = blockIdx.x >> 8;
    const int chunk = blockIdx.x & 255;
    const int row0  = chunk * 16;

    // A-frag: A[m=cl][k = kk*32 + quad*8 + j], k = h index; scale by w = sev/se
    const float* gp = gate + ((size_t)b * NN + row0 + cl) * HH + quad * 8;

    bf8v a2[2];
    #pragma unroll
    for (int kk = 0; kk < 2; ++kk) {
        f4v g0 = *(const f4v*)(gp + kk * 32);
        f4v g1 = *(const f4v*)(gp + kk * 32 + 4);
        const int hb = kk * 32 + quad * 8;
        f4v s0 = *(const f4v*)(se  + b * HH + hb);
        f4v s1 = *(const f4v*)(se  + b * HH + hb + 4);
        f4v v0 = *(const f4v*)(sev + b * HH + hb);
        f4v v1 = *(const f4v*)(sev + b * HH + hb + 4);
        #pragma unroll
        for (int j = 0; j < 4; ++j) {
            a2[kk][j]     = (__bf16)(g0[j] * __fdividef(v0[j], s0[j]));
            a2[kk][j + 4] = (__bf16)(g1[j] * __fdividef(v1[j], s1[j]));
        }
    }

    // B[k=h][n=d] = Wp[d][h], h-contiguous 16B per lane
    const bf16* wp = cWp + (size_t)cl * HH + quad * 8;
    const size_t outbase = ((size_t)b * NN + row0 + quad * 4) * DD;

    #pragma unroll 4
    for (int nt = 0; nt < 16; ++nt) {
        const int d0 = wave * 256 + nt * 16;
        f4v o = (f4v){0.f, 0.f, 0.f, 0.f};
        o = mfma16x16x32(a2[0], ldg8(wp + (size_t)d0 * HH), o);
        o = mfma16x16x32(a2[1], ldg8(wp + (size_t)d0 * HH + 32), o);
        const int dcol = d0 + cl;
        const float bpd = bp[dcol];
        #pragma unroll
        for (int r = 0; r < 4; ++r)
            out[outbase + (size_t)r * DD + dcol] = o[r] + bpd;
    }
}

extern "C" void kernel_launch(void* const* d_in, const int* in_sizes, int n_in,
                              void* d_out, int out_size, void* d_ws, size_t ws_size,
                              hipStream_t stream)
{
    const float* query = (const float*)d_in[0];
    const float* key_  = (const float*)d_in[1];
    const float* value = (const float*)d_in[2];
    const float* Wq = (const float*)d_in[3];
    const float* bq = (const float*)d_in[4];
    const float* Wk = (const float*)d_in[5];
    const float* bk = (const float*)d_in[6];
    const float* Wv = (const float*)d_in[7];
    const float* bv = (const float*)d_in[8];
    const float* Wp = (const float*)d_in[9];
    const float* bp = (const float*)d_in[10];
    float* out = (float*)d_out;

    // ws layout: [se 512f | sev 512f | pad to 4096B | cw 512KB bf16 | gate 8MB f32]
    float* se   = (float*)d_ws;
    float* sev  = se + BB * HH;
    bf16*  cw   = (bf16*)((char*)d_ws + 4096);
    float* gate = (float*)((char*)d_ws + 4096 + 4 * 65536 * sizeof(bf16));

    // ws is re-poisoned before every launch — zero the atomic accumulators.
    hipMemsetAsync(d_ws, 0, 2 * BB * HH * sizeof(float), stream);

    convert_weights_kernel<<<dim3(256), dim3(256), 0, stream>>>(Wq, Wk, Wv, Wp, cw);
    proj_kernel<<<dim3(2048), dim3(256), 0, stream>>>(
        query, key_, value, cw, bq, bk, bv, se, sev, gate);
    out_kernel<<<dim3(2048), dim3(256), 0, stream>>>(
        gate, cw + 3 * 65536, bp, se, sev, out);
}

// Round 2
// 484.765 us; speedup vs baseline: 1.2662x; 1.2662x over previous
//
#include <hip/hip_runtime.h>
#include <hip/hip_bf16.h>

#define BB 8
#define NN 4096
#define DD 1024
#define HH 64

typedef __bf16 bf8v __attribute__((ext_vector_type(8)));
typedef __bf16 bf4v __attribute__((ext_vector_type(4)));
typedef float  f4v  __attribute__((ext_vector_type(4)));
typedef __hip_bfloat16 bf16;

__device__ __forceinline__ f4v mfma16x16x32(bf8v a, bf8v b, f4v c) {
    return __builtin_amdgcn_mfma_f32_16x16x32_bf16(a, b, c, 0, 0, 0);
}

__device__ __forceinline__ bf8v pack8(f4v a, f4v b) {
    bf8v r;
    #pragma unroll
    for (int i = 0; i < 4; ++i) { r[i] = (__bf16)a[i]; r[i + 4] = (__bf16)b[i]; }
    return r;
}

__device__ __forceinline__ bf8v ldg8(const bf16* p) { return *(const bf8v*)p; }

// async global->LDS DMA, 16B per lane. Dest = wave-uniform base + lane*16;
// src is per-lane (this is how the XOR swizzle is applied: permuted source).
__device__ __forceinline__ void gload_lds16(const float* g, float* l) {
    __builtin_amdgcn_global_load_lds(
        (const __attribute__((address_space(1))) void*)g,
        (__attribute__((address_space(3))) void*)l,
        16, 0, 0);
}

// Kernel 0: convert the 4 weight matrices to bf16 in workspace: [Wq | Wk | Wv | Wp]
__global__ __launch_bounds__(256) void convert_weights_kernel(
    const float* __restrict__ Wq, const float* __restrict__ Wk,
    const float* __restrict__ Wv, const float* __restrict__ Wp,
    bf16* __restrict__ cw)
{
    const int idx = blockIdx.x * 256 + threadIdx.x;
    const int t = idx >> 14;
    const int e = (idx & 16383) * 4;
    const float* src = (t == 0) ? Wq : (t == 1) ? Wk : (t == 2) ? Wv : Wp;
    f4v x = *(const f4v*)(src + e);
    bf4v r;
    #pragma unroll
    for (int i = 0; i < 4; ++i) r[i] = (__bf16)x[i];
    *(bf4v*)(cw + t * 65536 + e) = r;
}

// Kernel 1: fused q/k/v projections with explicit global_load_lds pipeline.
//   blocks [0,512):   k,v -> exp -> se/sev atomics
//   blocks [512,1024): q -> sigmoid -> fp32 gate
// 4 waves/block, each wave owns 16 rows x all 64 h. Per k-step (BK=32 fp32):
//   - A tile (16 rows x 32 k = 2KB/stream) DMA'd to wave-private LDS, 2-deep
//     ping-pong; one "s_waitcnt vmcnt(0) lgkmcnt(0)" fence per step, NO barriers
//     (LDS regions are wave-private; vmcnt is per-wave).
//   - LDS row stride is 128B (16-way conflict) -> both-sides XOR swizzle:
//     linear DMA dest, inverse-permuted global src (chunk c = (lane&7)^(lane>>3)),
//     XOR'd ds_read offsets -> 2-way (free).
//   - weights: plain b128 loads from L2-resident cw; compiler counts them in
//     its own vmcnt waits (issued before next stage in program order).
__global__ __launch_bounds__(256, 4) void proj_kernel(
    const float* __restrict__ query, const float* __restrict__ key,
    const float* __restrict__ value, const bf16* __restrict__ cw,
    const float* __restrict__ bq, const float* __restrict__ bk,
    const float* __restrict__ bv,
    float* __restrict__ se, float* __restrict__ sev,
    float* __restrict__ gate)
{
    // [buf][wave][16 rows x 32 k] fp32, content XOR-swizzled in 16B chunks
    __shared__ __align__(16) float As0[2][4][512];   // key / query
    __shared__ __align__(16) float As1[2][4][512];   // value (kv blocks only)

    const int lane = threadIdx.x & 63;
    const int wave = threadIdx.x >> 6;
    const int cl   = lane & 15;   // A row (m) / C col (h)
    const int quad = lane >> 4;

    const int is_q = blockIdx.x >> 9;
    const int bid  = blockIdx.x & 511;
    const int b     = bid >> 6;
    const int chunk = bid & 63;
    const int row0  = chunk * 64 + wave * 16;

    // ---- staging source mapping (inverse swizzle) ----
    // inst j (j=0,1), lane i writes LDS byte p = j*1024 + i*16.
    // LDS[p] must hold global chunk (r = j*8 + i/8, c = (i&7) ^ (r&7)).
    const int sr = lane >> 3;                 // 0..7; rows j*8+sr
    const int sc = (lane & 7) ^ sr;           // swizzled k-chunk (16B units)
    const size_t soff0 = ((size_t)b * NN + row0 + sr) * DD + sc * 4;
    const size_t soff1 = soff0 + (size_t)8 * DD;

    // ---- read-side swizzled offsets (floats) ----
    const int sw  = cl & 7;
    const int flo = cl * 32 + ((((quad * 2)    ) ^ sw) << 2);
    const int fhi = cl * 32 + ((((quad * 2) + 1) ^ sw) << 2);

    if (!is_q) {
        const float* kb = key   + soff0;
        const float* vb = value + soff0;
        const bf16* wkb = cw + 1 * 65536 + (size_t)cl * DD + quad * 8;
        const bf16* wvb = cw + 2 * 65536 + (size_t)cl * DD + quad * 8;

        f4v kacc[4], vacc[4];
        #pragma unroll
        for (int i = 0; i < 4; ++i) {
            kacc[i] = (f4v){0.f, 0.f, 0.f, 0.f};
            vacc[i] = (f4v){0.f, 0.f, 0.f, 0.f};
        }

        // prologue: stage step 0 into buf 0
        gload_lds16(kb,            &As0[0][wave][0]);
        gload_lds16(kb + 8 * DD,   &As0[0][wave][256]);
        gload_lds16(vb,            &As1[0][wave][0]);
        gload_lds16(vb + 8 * DD,   &As1[0][wave][256]);

        #pragma unroll 2
        for (int t = 0; t < 32; ++t) {
            // drain own DMA (stage t) + all prior LDS reads; fences the
            // iteration so no memory op crosses (compiler can't unwind it)
            asm volatile("s_waitcnt vmcnt(0) lgkmcnt(0)" ::: "memory");
            const int bb = t & 1;
            const float* ak = &As0[bb][wave][0];
            const float* av = &As1[bb][wave][0];
            f4v klo = *(const f4v*)(ak + flo);
            f4v khi = *(const f4v*)(ak + fhi);
            f4v vlo = *(const f4v*)(av + flo);
            f4v vhi = *(const f4v*)(av + fhi);

            const int k0 = t * 32;
            bf8v wk8[4], wv8[4];
            #pragma unroll
            for (int ht = 0; ht < 4; ++ht) {
                wk8[ht] = ldg8(wkb + (size_t)ht * 16 * DD + k0);
                wv8[ht] = ldg8(wvb + (size_t)ht * 16 * DD + k0);
            }

            if (t < 31) {                     // stage t+1 into other buf
                const int nb = bb ^ 1;
                const int kn = (t + 1) * 32;
                gload_lds16(kb + kn,          &As0[nb][wave][0]);
                gload_lds16(kb + 8 * DD + kn, &As0[nb][wave][256]);
                gload_lds16(vb + kn,          &As1[nb][wave][0]);
                gload_lds16(vb + 8 * DD + kn, &As1[nb][wave][256]);
            }

            bf8v akf = pack8(klo, khi);
            bf8v avf = pack8(vlo, vhi);
            #pragma unroll
            for (int ht = 0; ht < 4; ++ht) {
                kacc[ht] = mfma16x16x32(akf, wk8[ht], kacc[ht]);
                vacc[ht] = mfma16x16x32(avf, wv8[ht], vacc[ht]);
            }
        }

        // C layout: col = cl (h), row = quad*4 + r; reduce rows, then quads.
        #pragma unroll
        for (int ht = 0; ht < 4; ++ht) {
            const int h = ht * 16 + cl;
            const float bkh = bk[h];
            const float bvh = bv[h];
            float sep = 0.f, sevp = 0.f;
            #pragma unroll
            for (int r = 0; r < 4; ++r) {
                float e = __expf(kacc[ht][r] + bkh);
                sep  += e;
                sevp += e * (vacc[ht][r] + bvh);
            }
            sep  += __shfl_xor(sep, 16, 64);
            sevp += __shfl_xor(sevp, 16, 64);
            sep  += __shfl_xor(sep, 32, 64);
            sevp += __shfl_xor(sevp, 32, 64);
            if (quad == 0) {
                atomicAdd(&se[b * HH + h], sep);
                atomicAdd(&sev[b * HH + h], sevp);
            }
        }
    } else {
        const float* qb = query + soff0;
        const bf16* wqb = cw + (size_t)cl * DD + quad * 8;

        f4v qacc[4];
        #pragma unroll
        for (int i = 0; i < 4; ++i) qacc[i] = (f4v){0.f, 0.f, 0.f, 0.f};

        gload_lds16(qb,          &As0[0][wave][0]);
        gload_lds16(qb + 8 * DD, &As0[0][wave][256]);

        #pragma unroll 2
        for (int t = 0; t < 32; ++t) {
            asm volatile("s_waitcnt vmcnt(0) lgkmcnt(0)" ::: "memory");
            const int bb = t & 1;
            const float* aq = &As0[bb][wave][0];
            f4v qlo = *(const f4v*)(aq + flo);
            f4v qhi = *(const f4v*)(aq + fhi);

            const int k0 = t * 32;
            bf8v wq8[4];
            #pragma unroll
            for (int ht = 0; ht < 4; ++ht)
                wq8[ht] = ldg8(wqb + (size_t)ht * 16 * DD + k0);

            if (t < 31) {
                const int nb = bb ^ 1;
                const int kn = (t + 1) * 32;
                gload_lds16(qb + kn,          &As0[nb][wave][0]);
                gload_lds16(qb + 8 * DD + kn, &As0[nb][wave][256]);
            }

            bf8v aqf = pack8(qlo, qhi);
            #pragma unroll
            for (int ht = 0; ht < 4; ++ht)
                qacc[ht] = mfma16x16x32(aqf, wq8[ht], qacc[ht]);
        }

        // gate = sigmoid(q + bq), fp32 (same rounding points as round 1)
        const size_t gbase = ((size_t)b * NN + row0 + quad * 4) * HH;
        #pragma unroll
        for (int ht = 0; ht < 4; ++ht) {
            const int h = ht * 16 + cl;
            const float bqh = bq[h];
            #pragma unroll
            for (int r = 0; r < 4; ++r) {
                float qv = qacc[ht][r] + bqh;
                float sg = 1.0f / (1.0f + __expf(-qv));
                gate[gbase + (size_t)r * HH + h] = sg;
            }
        }
    }
}

// Kernel 2: out[b,n,:] = (gate[b,n,:] * (sev/se)[b,:]) @ Wp^T + bp
// (unchanged from round 1 — gate read 8MB L3-resident, write-bound on 134MB)
__global__ __launch_bounds__(256) void out_kernel(
    const float* __restrict__ gate, const bf16* __restrict__ cWp,
    const float* __restrict__ bp, const float* __restrict__ se,
    const float* __restrict__ sev, float* __restrict__ out)
{
    const int lane = threadIdx.x & 63;
    const int wave = threadIdx.x >> 6;
    const int cl   = lane & 15;
    const int quad = lane >> 4;
    const int b     = blockIdx.x >> 8;
    const int chunk = blockIdx.x & 255;
    const int row0  = chunk * 16;

    const float* gp = gate + ((size_t)b * NN + row0 + cl) * HH + quad * 8;

    bf8v a2[2];
    #pragma unroll
    for (int kk = 0; kk < 2; ++kk) {
        f4v g0 = *(const f4v*)(gp + kk * 32);
        f4v g1 = *(const f4v*)(gp + kk * 32 + 4);
        const int hb = kk * 32 + quad * 8;
        f4v s0 = *(const f4v*)(se  + b * HH + hb);
        f4v s1 = *(const f4v*)(se  + b * HH + hb + 4);
        f4v v0 = *(const f4v*)(sev + b * HH + hb);
        f4v v1 = *(const f4v*)(sev + b * HH + hb + 4);
        #pragma unroll
        for (int j = 0; j < 4; ++j) {
            a2[kk][j]     = (__bf16)(g0[j] * __fdividef(v0[j], s0[j]));
            a2[kk][j + 4] = (__bf16)(g1[j] * __fdividef(v1[j], s1[j]));
        }
    }

    const bf16* wp = cWp + (size_t)cl * HH + quad * 8;
    const size_t outbase = ((size_t)b * NN + row0 + quad * 4) * DD;

    #pragma unroll 4
    for (int nt = 0; nt < 16; ++nt) {
        const int d0 = wave * 256 + nt * 16;
        f4v o = (f4v){0.f, 0.f, 0.f, 0.f};
        o = mfma16x16x32(a2[0], ldg8(wp + (size_t)d0 * HH), o);
        o = mfma16x16x32(a2[1], ldg8(wp + (size_t)d0 * HH + 32), o);
        const int dcol = d0 + cl;
        const float bpd = bp[dcol];
        #pragma unroll
        for (int r = 0; r < 4; ++r)
            out[outbase + (size_t)r * DD + dcol] = o[r] + bpd;
    }
}

extern "C" void kernel_launch(void* const* d_in, const int* in_sizes, int n_in,
                              void* d_out, int out_size, void* d_ws, size_t ws_size,
                              hipStream_t stream)
{
    const float* query = (const float*)d_in[0];
    const float* key_  = (const float*)d_in[1];
    const float* value = (const float*)d_in[2];
    const float* Wq = (const float*)d_in[3];
    const float* bq = (const float*)d_in[4];
    const float* Wk = (const float*)d_in[5];
    const float* bk = (const float*)d_in[6];
    const float* Wv = (const float*)d_in[7];
    const float* bv = (const float*)d_in[8];
    const float* Wp = (const float*)d_in[9];
    const float* bp = (const float*)d_in[10];
    float* out = (float*)d_out;

    // ws layout: [se 512f | sev 512f | pad to 4096B | cw 512KB bf16 | gate 8MB f32]
    float* se   = (float*)d_ws;
    float* sev  = se + BB * HH;
    bf16*  cw   = (bf16*)((char*)d_ws + 4096);
    float* gate = (float*)((char*)d_ws + 4096 + 4 * 65536 * sizeof(bf16));

    // ws is re-poisoned before every launch — zero the atomic accumulators.
    hipMemsetAsync(d_ws, 0, 2 * BB * HH * sizeof(float), stream);

    convert_weights_kernel<<<dim3(256), dim3(256), 0, stream>>>(Wq, Wk, Wv, Wp, cw);
    proj_kernel<<<dim3(1024), dim3(256), 0, stream>>>(
        query, key_, value, cw, bq, bk, bv, se, sev, gate);
    out_kernel<<<dim3(2048), dim3(256), 0, stream>>>(
        gate, cw + 3 * 65536, bp, se, sev, out);
}

// Round 3
// 483.106 us; speedup vs baseline: 1.2706x; 1.0034x over previous
//
#include <hip/hip_runtime.h>
#include <hip/hip_bf16.h>

#define BB 8
#define NN 4096
#define DD 1024
#define HH 64

typedef __bf16 bf8v __attribute__((ext_vector_type(8)));
typedef __bf16 bf4v __attribute__((ext_vector_type(4)));
typedef float  f4v  __attribute__((ext_vector_type(4)));
typedef __hip_bfloat16 bf16;

#define SB0() __builtin_amdgcn_sched_barrier(0)

__device__ __forceinline__ f4v mfma16x16x32(bf8v a, bf8v b, f4v c) {
    return __builtin_amdgcn_mfma_f32_16x16x32_bf16(a, b, c, 0, 0, 0);
}

__device__ __forceinline__ bf8v pack8(f4v a, f4v b) {
    bf8v r;
    #pragma unroll
    for (int i = 0; i < 4; ++i) { r[i] = (__bf16)a[i]; r[i + 4] = (__bf16)b[i]; }
    return r;
}

__device__ __forceinline__ bf8v ldg8(const bf16* p) { return *(const bf8v*)p; }

// async global->LDS DMA, 16B per lane. Dest = wave-uniform base + lane*16;
// src is per-lane (the XOR swizzle is applied via the permuted source).
__device__ __forceinline__ void gload_lds16(const float* g, float* l) {
    __builtin_amdgcn_global_load_lds(
        (const __attribute__((address_space(1))) void*)g,
        (__attribute__((address_space(3))) void*)l,
        16, 0, 0);
}

// Kernel 0: convert the 4 weight matrices to bf16 in workspace: [Wq | Wk | Wv | Wp]
__global__ __launch_bounds__(256) void convert_weights_kernel(
    const float* __restrict__ Wq, const float* __restrict__ Wk,
    const float* __restrict__ Wv, const float* __restrict__ Wp,
    bf16* __restrict__ cw)
{
    const int idx = blockIdx.x * 256 + threadIdx.x;
    const int t = idx >> 14;
    const int e = (idx & 16383) * 4;
    const float* src = (t == 0) ? Wq : (t == 1) ? Wk : (t == 2) ? Wv : Wp;
    f4v x = *(const f4v*)(src + e);
    bf4v r;
    #pragma unroll
    for (int i = 0; i < 4; ++i) r[i] = (__bf16)x[i];
    *(bf4v*)(cw + t * 65536 + e) = r;
}

// Kernel 1: fused q/k/v projections, counted-vmcnt pipeline (T4).
//   blocks [0,512):   k,v -> exp -> se/sev atomics
//   blocks [512,1024): q -> sigmoid -> fp32 gate
// Per wave: 16 rows x 64 h, K=1024 in 32 steps of BK=32.
//   - A tiles DMA'd (global_load_lds) into a wave-private 3-deep LDS ring;
//     stage t+2 issued at iter t. Top-of-iter fence = counted vmcnt:
//     outstanding set there is [DMA(t) | W(t) | DMA(t+1)] -> kv: vmcnt(12),
//     q: vmcnt(10); last iter: vmcnt(8). NEVER vmcnt(0) in the loop, so the
//     oldest DMA was issued 2 iterations ago -> zero steady-state stall.
//   - Weight frags (L2-resident) prefetched 1 iter ahead into w[2][4] regs
//     (static indices after full unroll), so the compiler's own pre-MFMA
//     vmcnt is satisfied by year-old loads.
//   - No barriers (LDS ring is wave-private; vmcnt is per-wave). Prologue
//     issue order pinned with sched_barrier(0) so DMA(0) is oldest.
//   - XOR swizzle (both-sides): linear DMA dest, inverse-permuted global
//     source chunks, XOR'd ds_read offsets.
__global__ __launch_bounds__(256, 3) void proj_kernel(
    const float* __restrict__ query, const float* __restrict__ key,
    const float* __restrict__ value, const bf16* __restrict__ cw,
    const float* __restrict__ bq, const float* __restrict__ bk,
    const float* __restrict__ bv,
    float* __restrict__ se, float* __restrict__ sev,
    float* __restrict__ gate)
{
    // [stage][wave][16 rows x 32 k] fp32, content XOR-swizzled in 16B chunks
    __shared__ __align__(16) float As0[3][4][512];   // key / query
    __shared__ __align__(16) float As1[3][4][512];   // value (kv blocks only)

    const int lane = threadIdx.x & 63;
    const int wave = threadIdx.x >> 6;
    const int cl   = lane & 15;   // A row (m) / C col (h)
    const int quad = lane >> 4;

    const int is_q = blockIdx.x >> 9;
    const int bid  = blockIdx.x & 511;
    const int b     = bid >> 6;
    const int chunk = bid & 63;
    const int row0  = chunk * 64 + wave * 16;

    // staging source mapping (inverse swizzle):
    // inst j (j=0,1), lane i writes LDS byte p = j*1024 + i*16;
    // LDS[p] holds global chunk (r = j*8 + i/8, c = (i&7) ^ (r&7)).
    const int sr = lane >> 3;
    const int sc = (lane & 7) ^ sr;
    const size_t soff0 = ((size_t)b * NN + row0 + sr) * DD + sc * 4;

    // read-side swizzled offsets (floats)
    const int sw  = cl & 7;
    const int flo = cl * 32 + ((((quad * 2)    ) ^ sw) << 2);
    const int fhi = cl * 32 + ((((quad * 2) + 1) ^ sw) << 2);

    if (!is_q) {
        const float* kb = key   + soff0;
        const float* vb = value + soff0;
        const bf16* wkb = cw + 1 * 65536 + (size_t)cl * DD + quad * 8;
        const bf16* wvb = cw + 2 * 65536 + (size_t)cl * DD + quad * 8;

        f4v kacc[4], vacc[4];
        #pragma unroll
        for (int i = 0; i < 4; ++i) {
            kacc[i] = (f4v){0.f, 0.f, 0.f, 0.f};
            vacc[i] = (f4v){0.f, 0.f, 0.f, 0.f};
        }

        bf8v wk8[2][4], wv8[2][4];

        // ---- prologue: DMA(0) MUST be the oldest 4 vmcnt events ----
        gload_lds16(kb,          &As0[0][wave][0]);
        gload_lds16(kb + 8 * DD, &As0[0][wave][256]);
        gload_lds16(vb,          &As1[0][wave][0]);
        gload_lds16(vb + 8 * DD, &As1[0][wave][256]);
        SB0();
        #pragma unroll
        for (int ht = 0; ht < 4; ++ht) {
            wk8[0][ht] = ldg8(wkb + (size_t)ht * 16 * DD);
            wv8[0][ht] = ldg8(wvb + (size_t)ht * 16 * DD);
        }
        SB0();
        gload_lds16(kb + 32,          &As0[1][wave][0]);
        gload_lds16(kb + 8 * DD + 32, &As0[1][wave][256]);
        gload_lds16(vb + 32,          &As1[1][wave][0]);
        gload_lds16(vb + 8 * DD + 32, &As1[1][wave][256]);

        #pragma unroll
        for (int t = 0; t < 32; ++t) {
            // outstanding here: [DMA(t) 4 | W(t) 8 | DMA(t+1) 4] (last iter: no DMA(t+1))
            if (t < 31) { asm volatile("s_waitcnt vmcnt(12)" ::: "memory"); }
            else        { asm volatile("s_waitcnt vmcnt(8)"  ::: "memory"); }
            SB0();
            const int st = t % 3;
            const float* ak = &As0[st][wave][0];
            const float* av = &As1[st][wave][0];
            f4v klo = *(const f4v*)(ak + flo);
            f4v khi = *(const f4v*)(ak + fhi);
            f4v vlo = *(const f4v*)(av + flo);
            f4v vhi = *(const f4v*)(av + fhi);
            bf8v akf = pack8(klo, khi);
            bf8v avf = pack8(vlo, vhi);

            const int cb = t & 1, nb = cb ^ 1;
            #pragma unroll
            for (int ht = 0; ht < 4; ++ht) {
                kacc[ht] = mfma16x16x32(akf, wk8[cb][ht], kacc[ht]);
                vacc[ht] = mfma16x16x32(avf, wv8[cb][ht], vacc[ht]);
            }

            if (t < 31) {            // prefetch W(t+1)
                const int k0 = (t + 1) * 32;
                #pragma unroll
                for (int ht = 0; ht < 4; ++ht) {
                    wk8[nb][ht] = ldg8(wkb + (size_t)ht * 16 * DD + k0);
                    wv8[nb][ht] = ldg8(wvb + (size_t)ht * 16 * DD + k0);
                }
            }
            if (t < 30) {            // stage DMA(t+2)
                const int kn = (t + 2) * 32;
                const int sn = (t + 2) % 3;
                gload_lds16(kb + kn,          &As0[sn][wave][0]);
                gload_lds16(kb + 8 * DD + kn, &As0[sn][wave][256]);
                gload_lds16(vb + kn,          &As1[sn][wave][0]);
                gload_lds16(vb + 8 * DD + kn, &As1[sn][wave][256]);
            }
        }

        // C layout: col = cl (h), row = quad*4 + r; reduce rows, then quads.
        #pragma unroll
        for (int ht = 0; ht < 4; ++ht) {
            const int h = ht * 16 + cl;
            const float bkh = bk[h];
            const float bvh = bv[h];
            float sep = 0.f, sevp = 0.f;
            #pragma unroll
            for (int r = 0; r < 4; ++r) {
                float e = __expf(kacc[ht][r] + bkh);
                sep  += e;
                sevp += e * (vacc[ht][r] + bvh);
            }
            sep  += __shfl_xor(sep, 16, 64);
            sevp += __shfl_xor(sevp, 16, 64);
            sep  += __shfl_xor(sep, 32, 64);
            sevp += __shfl_xor(sevp, 32, 64);
            if (quad == 0) {
                atomicAdd(&se[b * HH + h], sep);
                atomicAdd(&sev[b * HH + h], sevp);
            }
        }
    } else {
        const float* qb = query + soff0;
        const bf16* wqb = cw + (size_t)cl * DD + quad * 8;

        f4v qacc[4];
        #pragma unroll
        for (int i = 0; i < 4; ++i) qacc[i] = (f4v){0.f, 0.f, 0.f, 0.f};

        bf8v wq8[2][4];

        // ---- prologue: DMA(0) oldest ----
        gload_lds16(qb,          &As0[0][wave][0]);
        gload_lds16(qb + 8 * DD, &As0[0][wave][256]);
        SB0();
        #pragma unroll
        for (int ht = 0; ht < 4; ++ht)
            wq8[0][ht] = ldg8(wqb + (size_t)ht * 16 * DD);
        SB0();
        gload_lds16(qb + 32,          &As0[1][wave][0]);
        gload_lds16(qb + 8 * DD + 32, &As0[1][wave][256]);

        #pragma unroll
        for (int t = 0; t < 32; ++t) {
            // outstanding here: [DMA(t) 2 | W(t) 8 | DMA(t+1) 2]
            if (t < 31) { asm volatile("s_waitcnt vmcnt(10)" ::: "memory"); }
            else        { asm volatile("s_waitcnt vmcnt(8)"  ::: "memory"); }
            SB0();
            const int st = t % 3;
            const float* aq = &As0[st][wave][0];
            f4v qlo = *(const f4v*)(aq + flo);
            f4v qhi = *(const f4v*)(aq + fhi);
            bf8v aqf = pack8(qlo, qhi);

            const int cb = t & 1, nb = cb ^ 1;
            #pragma unroll
            for (int ht = 0; ht < 4; ++ht)
                qacc[ht] = mfma16x16x32(aqf, wq8[cb][ht], qacc[ht]);

            if (t < 31) {
                const int k0 = (t + 1) * 32;
                #pragma unroll
                for (int ht = 0; ht < 4; ++ht)
                    wq8[nb][ht] = ldg8(wqb + (size_t)ht * 16 * DD + k0);
            }
            if (t < 30) {
                const int kn = (t + 2) * 32;
                const int sn = (t + 2) % 3;
                gload_lds16(qb + kn,          &As0[sn][wave][0]);
                gload_lds16(qb + 8 * DD + kn, &As0[sn][wave][256]);
            }
        }

        // gate = sigmoid(q + bq), fp32
        const size_t gbase = ((size_t)b * NN + row0 + quad * 4) * HH;
        #pragma unroll
        for (int ht = 0; ht < 4; ++ht) {
            const int h = ht * 16 + cl;
            const float bqh = bq[h];
            #pragma unroll
            for (int r = 0; r < 4; ++r) {
                float qv = qacc[ht][r] + bqh;
                float sg = 1.0f / (1.0f + __expf(-qv));
                gate[gbase + (size_t)r * HH + h] = sg;
            }
        }
    }
}

// Kernel 2: out[b,n,:] = (gate[b,n,:] * (sev/se)[b,:]) @ Wp^T + bp
__global__ __launch_bounds__(256) void out_kernel(
    const float* __restrict__ gate, const bf16* __restrict__ cWp,
    const float* __restrict__ bp, const float* __restrict__ se,
    const float* __restrict__ sev, float* __restrict__ out)
{
    const int lane = threadIdx.x & 63;
    const int wave = threadIdx.x >> 6;
    const int cl   = lane & 15;
    const int quad = lane >> 4;
    const int b     = blockIdx.x >> 8;
    const int chunk = blockIdx.x & 255;
    const int row0  = chunk * 16;

    const float* gp = gate + ((size_t)b * NN + row0 + cl) * HH + quad * 8;

    bf8v a2[2];
    #pragma unroll
    for (int kk = 0; kk < 2; ++kk) {
        f4v g0 = *(const f4v*)(gp + kk * 32);
        f4v g1 = *(const f4v*)(gp + kk * 32 + 4);
        const int hb = kk * 32 + quad * 8;
        f4v s0 = *(const f4v*)(se  + b * HH + hb);
        f4v s1 = *(const f4v*)(se  + b * HH + hb + 4);
        f4v v0 = *(const f4v*)(sev + b * HH + hb);
        f4v v1 = *(const f4v*)(sev + b * HH + hb + 4);
        #pragma unroll
        for (int j = 0; j < 4; ++j) {
            a2[kk][j]     = (__bf16)(g0[j] * __fdividef(v0[j], s0[j]));
            a2[kk][j + 4] = (__bf16)(g1[j] * __fdividef(v1[j], s1[j]));
        }
    }

    const bf16* wp = cWp + (size_t)cl * HH + quad * 8;
    const size_t outbase = ((size_t)b * NN + row0 + quad * 4) * DD;

    #pragma unroll 4
    for (int nt = 0; nt < 16; ++nt) {
        const int d0 = wave * 256 + nt * 16;
        f4v o = (f4v){0.f, 0.f, 0.f, 0.f};
        o = mfma16x16x32(a2[0], ldg8(wp + (size_t)d0 * HH), o);
        o = mfma16x16x32(a2[1], ldg8(wp + (size_t)d0 * HH + 32), o);
        const int dcol = d0 + cl;
        const float bpd = bp[dcol];
        #pragma unroll
        for (int r = 0; r < 4; ++r)
            out[outbase + (size_t)r * DD + dcol] = o[r] + bpd;
    }
}

extern "C" void kernel_launch(void* const* d_in, const int* in_sizes, int n_in,
                              void* d_out, int out_size, void* d_ws, size_t ws_size,
                              hipStream_t stream)
{
    const float* query = (const float*)d_in[0];
    const float* key_  = (const float*)d_in[1];
    const float* value = (const float*)d_in[2];
    const float* Wq = (const float*)d_in[3];
    const float* bq = (const float*)d_in[4];
    const float* Wk = (const float*)d_in[5];
    const float* bk = (const float*)d_in[6];
    const float* Wv = (const float*)d_in[7];
    const float* bv = (const float*)d_in[8];
    const float* Wp = (const float*)d_in[9];
    const float* bp = (const float*)d_in[10];
    float* out = (float*)d_out;

    // ws layout: [se 512f | sev 512f | pad to 4096B | cw 512KB bf16 | gate 8MB f32]
    float* se   = (float*)d_ws;
    float* sev  = se + BB * HH;
    bf16*  cw   = (bf16*)((char*)d_ws + 4096);
    float* gate = (float*)((char*)d_ws + 4096 + 4 * 65536 * sizeof(bf16));

    // ws is re-poisoned before every launch — zero the atomic accumulators.
    hipMemsetAsync(d_ws, 0, 2 * BB * HH * sizeof(float), stream);

    convert_weights_kernel<<<dim3(256), dim3(256), 0, stream>>>(Wq, Wk, Wv, Wp, cw);
    proj_kernel<<<dim3(1024), dim3(256), 0, stream>>>(
        query, key_, value, cw, bq, bk, bv, se, sev, gate);
    out_kernel<<<dim3(2048), dim3(256), 0, stream>>>(
        gate, cw + 3 * 65536, bp, se, sev, out);
}